// Round 1
// baseline (10756.614 us; speedup 1.0000x reference)
//
#include <hip/hip_runtime.h>

#define BB 64
#define TT 2048
#define FF 15
#define UU 256
#define N3 768
#define NP 128          // 128 k-pairs (256 rows) of U per column, in VGPRs as v2f16

typedef _Float16 half2v __attribute__((ext_vector_type(2)));

__device__ float  g_seq1[BB * TT * UU];          // 134 MB
__device__ float  g_xp[(size_t)BB * TT * N3];    // 402 MB (xp1 then xp2)
__device__ half2v g_U1h[NP * N3];
__device__ half2v g_U2h[NP * N3];

__device__ __forceinline__ float dot2f(half2v a, half2v b, float c) {
#if __has_builtin(__builtin_amdgcn_fdot2)
    return __builtin_amdgcn_fdot2(a, b, c, false);
#else
    return c + (float)a.x * (float)b.x + (float)a.y * (float)b.y;
#endif
}

// Pack U (fp32 [256][768]) into k-pair f16 layout: Uh[p*768+j] = {U[2p][j], U[2p+1][j]}
__global__ __launch_bounds__(256) void prep_uh(const float* __restrict__ U,
                                               half2v* __restrict__ Uh) {
    int idx = blockIdx.x * 256 + threadIdx.x;    // 0 .. 128*768-1
    int p = idx / N3, j = idx - p * N3;
    half2v v;
    v.x = (_Float16)U[(2 * p + 0) * N3 + j];
    v.y = (_Float16)U[(2 * p + 1) * N3 + j];
    Uh[idx] = v;
}

// xp1 = x @ W1 + b_in   (K=15, memory-bound)
__global__ __launch_bounds__(256) void gemm_k15(
    const float* __restrict__ x, const float* __restrict__ W1,
    const float* __restrict__ bin, float* __restrict__ C) {
    __shared__ float xr[8][FF];
    const int m0 = blockIdx.x * 8;
    const int j  = blockIdx.y * 256 + threadIdx.x;
    if (threadIdx.x < 8 * FF) {
        int r = threadIdx.x / FF, k = threadIdx.x - r * FF;
        xr[r][k] = x[(size_t)(m0 + r) * FF + k];
    }
    __syncthreads();
    float wv[FF];
#pragma unroll
    for (int k = 0; k < FF; k++) wv[k] = W1[k * N3 + j];
    const float bj = bin[j];
#pragma unroll
    for (int r = 0; r < 8; r++) {
        float a = bj;
#pragma unroll
        for (int k = 0; k < FF; k++) a += xr[r][k] * wv[k];
        C[(size_t)(m0 + r) * N3 + j] = a;
    }
}

// xp2 = seq1 @ W2 + b_in   (M=131072, N=768, K=256) tiled fp32 GEMM
__global__ __launch_bounds__(256) void gemm_xp(
    const float* __restrict__ A, const float* __restrict__ Bw,
    const float* __restrict__ bin, float* __restrict__ C) {
    __shared__ float As[16][64];
    __shared__ float Bs[16][64];
    const int tid = threadIdx.x;
    const int m0 = blockIdx.x * 64, n0 = blockIdx.y * 64;
    const int tm = (tid & 15) * 4;
    const int tn = (tid >> 4) * 4;
    float acc[4][4] = {};
    const int lm = tid >> 2, lk = (tid & 3) * 4;
    const int lkb = tid >> 4, ln = (tid & 15) * 4;
    for (int k0 = 0; k0 < 256; k0 += 16) {
        float4 av = *(const float4*)&A[(size_t)(m0 + lm) * 256 + k0 + lk];
        float4 bv = *(const float4*)&Bw[(size_t)(k0 + lkb) * N3 + n0 + ln];
        As[lk + 0][lm] = av.x; As[lk + 1][lm] = av.y;
        As[lk + 2][lm] = av.z; As[lk + 3][lm] = av.w;
        *(float4*)&Bs[lkb][ln] = bv;
        __syncthreads();
#pragma unroll
        for (int kk = 0; kk < 16; kk++) {
            float4 a = *(const float4*)&As[kk][tm];
            float4 b = *(const float4*)&Bs[kk][tn];
            acc[0][0] += a.x * b.x; acc[0][1] += a.x * b.y; acc[0][2] += a.x * b.z; acc[0][3] += a.x * b.w;
            acc[1][0] += a.y * b.x; acc[1][1] += a.y * b.y; acc[1][2] += a.y * b.z; acc[1][3] += a.y * b.w;
            acc[2][0] += a.z * b.x; acc[2][1] += a.z * b.y; acc[2][2] += a.z * b.z; acc[2][3] += a.z * b.w;
            acc[3][0] += a.w * b.x; acc[3][1] += a.w * b.y; acc[3][2] += a.w * b.z; acc[3][3] += a.w * b.w;
        }
        __syncthreads();
    }
#pragma unroll
    for (int i = 0; i < 4; i++) {
        float4 o = make_float4(acc[i][0] + bin[n0 + tn + 0], acc[i][1] + bin[n0 + tn + 1],
                               acc[i][2] + bin[n0 + tn + 2], acc[i][3] + bin[n0 + tn + 3]);
        *(float4*)&C[(size_t)(m0 + tm + i) * N3 + n0 + tn] = o;
    }
}

// 12 dot2s fed by one float4 (4 h-pairs) of broadcast h
#define DOT4PAIRS(HV, Q)                                     \
    {                                                        \
        half2v* hp_ = (half2v*)&(HV);                        \
        a0a = dot2f(hp_[0], u0[(Q) + 0], a0a);               \
        a1a = dot2f(hp_[0], u1[(Q) + 0], a1a);               \
        a2a = dot2f(hp_[0], u2[(Q) + 0], a2a);               \
        a0b = dot2f(hp_[1], u0[(Q) + 1], a0b);               \
        a1b = dot2f(hp_[1], u1[(Q) + 1], a1b);               \
        a2b = dot2f(hp_[1], u2[(Q) + 1], a2b);               \
        a0a = dot2f(hp_[2], u0[(Q) + 2], a0a);               \
        a1a = dot2f(hp_[2], u1[(Q) + 2], a1a);               \
        a2a = dot2f(hp_[2], u2[(Q) + 2], a2a);               \
        a0b = dot2f(hp_[3], u0[(Q) + 3], a0b);               \
        a1b = dot2f(hp_[3], u1[(Q) + 3], a1b);               \
        a2b = dot2f(hp_[3], u2[(Q) + 3], a2b);               \
    }

// GRU recurrence, one WG per batch element. 256 threads; thread j owns unit j,
// i.e. ALL THREE gate columns (z: j, r: j+256, hh: j+512) of U in 384 v2f16
// VGPRs. Gate math is thread-local (no pre[] exchange), h state is a register,
// packed-f16 h is double-buffered in LDS -> ONE barrier per timestep and 3x
// fewer LDS broadcast reads than the 768-thread version.
__global__ __launch_bounds__(256, 1) void gru_recur3(
    const half2v* __restrict__ Uh, const float* __restrict__ brec,
    const float* __restrict__ xp, float* __restrict__ seq_out,
    float* __restrict__ state_out, float* __restrict__ extra_out) {
    const int b = blockIdx.x, j = threadIdx.x;     // j in [0,256)

    __shared__ __align__(16) half2v h2s[2][NP];    // packed h (f16 pairs), dbuf

    // load U columns j, j+256, j+512 into VGPRs (coalesced across lanes)
    half2v u0[NP], u1[NP], u2[NP];
#pragma unroll
    for (int p = 0; p < NP; p++) {
        u0[p] = Uh[p * N3 + j];
        u1[p] = Uh[p * N3 + j + UU];
        u2[p] = Uh[p * N3 + j + 2 * UU];
    }
    const float br0 = brec[j], br1 = brec[j + UU], br2 = brec[j + 2 * UU];

    if (j < NP) { half2v z0; z0.x = (_Float16)0.f; z0.y = (_Float16)0.f; h2s[0][j] = z0; }
    float hst = 0.f;                               // fp32 h state, in-register
    __syncthreads();

    const float* __restrict__ xpb = xp + (size_t)b * TT * N3;
    float xz = xpb[j], xr = xpb[j + UU], xh = xpb[j + 2 * UU];

    for (int t = 0; t < TT; t++) {
        // prefetch next step's x-projection
        const float* xn = xpb + (size_t)(t + 1 < TT ? t + 1 : t) * N3;
        float xzn = xn[j], xrn = xn[j + UU], xhn = xn[j + 2 * UU];

        // rec_g = brec[g] + sum_k h[k] * U[k][col_g]  for g in {z, r, hh}
        float a0a = br0, a0b = 0.f, a1a = br1, a1b = 0.f, a2a = br2, a2b = 0.f;
        const float4* hb4 = (const float4*)h2s[t & 1];
#pragma unroll
        for (int p4 = 0; p4 < NP / 4; p4++) {
            float4 hv = hb4[p4];
            DOT4PAIRS(hv, 4 * p4);
        }
        float az = a0a + a0b, ar = a1a + a1b, ah = a2a + a2b;

        // gates, all thread-local
        float z  = 1.f / (1.f + __expf(-(xz + az)));
        float r  = 1.f / (1.f + __expf(-(xr + ar)));
        float hh = xh + r * ah;
        hh = hh > 0.f ? hh : 0.f;
        float hn = z * hst + (1.f - z) * hh;
        hst = hn;

        // pack h into f16 pairs for next step's broadcast
        float hp = __shfl_xor(hn, 1);
        if ((j & 1) == 0) {
            half2v pk; pk.x = (_Float16)hn; pk.y = (_Float16)hp;
            h2s[(t + 1) & 1][j >> 1] = pk;
        }
        if (seq_out) seq_out[(size_t)b * TT * UU + (size_t)t * UU + j] = hn;
        __syncthreads();                           // single barrier per step
        xz = xzn; xr = xrn; xh = xhn;
    }

    state_out[b * UU + j] = hst;
    if (extra_out) extra_out[b * UU + j] = hst;
}

extern "C" void kernel_launch(void* const* d_in, const int* in_sizes, int n_in,
                              void* d_out, int out_size, void* d_ws, size_t ws_size,
                              hipStream_t stream) {
    const float* x  = (const float*)d_in[0];
    const float* W1 = (const float*)d_in[1];
    const float* U1 = (const float*)d_in[2];
    const float* b1 = (const float*)d_in[3];
    const float* W2 = (const float*)d_in[4];
    const float* U2 = (const float*)d_in[5];
    const float* b2 = (const float*)d_in[6];
    float* out = (float*)d_out;

    half2v* U1h; hipGetSymbolAddress((void**)&U1h, HIP_SYMBOL(g_U1h));
    half2v* U2h; hipGetSymbolAddress((void**)&U2h, HIP_SYMBOL(g_U2h));
    float*  seq1; hipGetSymbolAddress((void**)&seq1, HIP_SYMBOL(g_seq1));
    float*  xp;   hipGetSymbolAddress((void**)&xp,   HIP_SYMBOL(g_xp));

    prep_uh<<<NP * N3 / 256, 256, 0, stream>>>(U1, U1h);
    prep_uh<<<NP * N3 / 256, 256, 0, stream>>>(U2, U2h);

    // layer 1
    gemm_k15<<<dim3(BB * TT / 8, 3), 256, 0, stream>>>(x, W1, b1, xp);
    gru_recur3<<<BB, 256, 0, stream>>>(U1h, b1 + N3, xp, seq1, out + BB * UU, nullptr);

    // layer 2
    gemm_xp<<<dim3(BB * TT / 64, N3 / 64), 256, 0, stream>>>(seq1, W2, b2, xp);
    gru_recur3<<<BB, 256, 0, stream>>>(U2h, b2 + N3, xp, nullptr, out + 2 * BB * UU, out);
}

// Round 2
// 5654.444 us; speedup vs baseline: 1.9023x; 1.9023x over previous
//
#include <hip/hip_runtime.h>

#define BB 64
#define TT 2048
#define FF 15
#define UU 256
#define N3 768
#define NP 128          // 128 k-pairs (256 rows) of U per column
#define NH 64           // k-pairs held per thread (half a column)

typedef _Float16 half2v __attribute__((ext_vector_type(2)));

__device__ float  g_seq1[BB * TT * UU];          // 134 MB
__device__ float  g_xp[(size_t)BB * TT * N3];    // 402 MB (xp1 then xp2)
__device__ half2v g_U1h[NP * N3];
__device__ half2v g_U2h[NP * N3];

__device__ __forceinline__ float dot2f(half2v a, half2v b, float c) {
#if __has_builtin(__builtin_amdgcn_fdot2)
    return __builtin_amdgcn_fdot2(a, b, c, false);
#else
    return c + (float)a.x * (float)b.x + (float)a.y * (float)b.y;
#endif
}

// Pack U (fp32 [256][768]) into k-pair f16 layout: Uh[p*768+j] = {U[2p][j], U[2p+1][j]}
__global__ __launch_bounds__(256) void prep_uh(const float* __restrict__ U,
                                               half2v* __restrict__ Uh) {
    int idx = blockIdx.x * 256 + threadIdx.x;    // 0 .. 128*768-1
    int p = idx / N3, j = idx - p * N3;
    half2v v;
    v.x = (_Float16)U[(2 * p + 0) * N3 + j];
    v.y = (_Float16)U[(2 * p + 1) * N3 + j];
    Uh[idx] = v;
}

// xp1 = x @ W1 + b_in   (K=15, memory-bound)
__global__ __launch_bounds__(256) void gemm_k15(
    const float* __restrict__ x, const float* __restrict__ W1,
    const float* __restrict__ bin, float* __restrict__ C) {
    __shared__ float xr[8][FF];
    const int m0 = blockIdx.x * 8;
    const int j  = blockIdx.y * 256 + threadIdx.x;
    if (threadIdx.x < 8 * FF) {
        int r = threadIdx.x / FF, k = threadIdx.x - r * FF;
        xr[r][k] = x[(size_t)(m0 + r) * FF + k];
    }
    __syncthreads();
    float wv[FF];
#pragma unroll
    for (int k = 0; k < FF; k++) wv[k] = W1[k * N3 + j];
    const float bj = bin[j];
#pragma unroll
    for (int r = 0; r < 8; r++) {
        float a = bj;
#pragma unroll
        for (int k = 0; k < FF; k++) a += xr[r][k] * wv[k];
        C[(size_t)(m0 + r) * N3 + j] = a;
    }
}

// xp2 = seq1 @ W2 + b_in   (M=131072, N=768, K=256) tiled fp32 GEMM
__global__ __launch_bounds__(256) void gemm_xp(
    const float* __restrict__ A, const float* __restrict__ Bw,
    const float* __restrict__ bin, float* __restrict__ C) {
    __shared__ float As[16][64];
    __shared__ float Bs[16][64];
    const int tid = threadIdx.x;
    const int m0 = blockIdx.x * 64, n0 = blockIdx.y * 64;
    const int tm = (tid & 15) * 4;
    const int tn = (tid >> 4) * 4;
    float acc[4][4] = {};
    const int lm = tid >> 2, lk = (tid & 3) * 4;
    const int lkb = tid >> 4, ln = (tid & 15) * 4;
    for (int k0 = 0; k0 < 256; k0 += 16) {
        float4 av = *(const float4*)&A[(size_t)(m0 + lm) * 256 + k0 + lk];
        float4 bv = *(const float4*)&Bw[(size_t)(k0 + lkb) * N3 + n0 + ln];
        As[lk + 0][lm] = av.x; As[lk + 1][lm] = av.y;
        As[lk + 2][lm] = av.z; As[lk + 3][lm] = av.w;
        *(float4*)&Bs[lkb][ln] = bv;
        __syncthreads();
#pragma unroll
        for (int kk = 0; kk < 16; kk++) {
            float4 a = *(const float4*)&As[kk][tm];
            float4 b = *(const float4*)&Bs[kk][tn];
            acc[0][0] += a.x * b.x; acc[0][1] += a.x * b.y; acc[0][2] += a.x * b.z; acc[0][3] += a.x * b.w;
            acc[1][0] += a.y * b.x; acc[1][1] += a.y * b.y; acc[1][2] += a.y * b.z; acc[1][3] += a.y * b.w;
            acc[2][0] += a.z * b.x; acc[2][1] += a.z * b.y; acc[2][2] += a.z * b.z; acc[2][3] += a.z * b.w;
            acc[3][0] += a.w * b.x; acc[3][1] += a.w * b.y; acc[3][2] += a.w * b.z; acc[3][3] += a.w * b.w;
        }
        __syncthreads();
    }
#pragma unroll
    for (int i = 0; i < 4; i++) {
        float4 o = make_float4(acc[i][0] + bin[n0 + tn + 0], acc[i][1] + bin[n0 + tn + 1],
                               acc[i][2] + bin[n0 + tn + 2], acc[i][3] + bin[n0 + tn + 3]);
        *(float4*)&C[(size_t)(m0 + tm + i) * N3 + n0 + tn] = o;
    }
}

// 12 dot2s fed by one float4 (4 h-pairs) of broadcast h
#define DOT4PAIRS(HV, Q)                                     \
    {                                                        \
        half2v* hp_ = (half2v*)&(HV);                        \
        a0a = dot2f(hp_[0], u0[(Q) + 0], a0a);               \
        a1a = dot2f(hp_[0], u1[(Q) + 0], a1a);               \
        a2a = dot2f(hp_[0], u2[(Q) + 0], a2a);               \
        a0b = dot2f(hp_[1], u0[(Q) + 1], a0b);               \
        a1b = dot2f(hp_[1], u1[(Q) + 1], a1b);               \
        a2b = dot2f(hp_[1], u2[(Q) + 1], a2b);               \
        a0a = dot2f(hp_[2], u0[(Q) + 2], a0a);               \
        a1a = dot2f(hp_[2], u1[(Q) + 2], a1a);               \
        a2a = dot2f(hp_[2], u2[(Q) + 2], a2a);               \
        a0b = dot2f(hp_[3], u0[(Q) + 3], a0b);               \
        a1b = dot2f(hp_[3], u1[(Q) + 3], a1b);               \
        a2b = dot2f(hp_[3], u2[(Q) + 3], a2b);               \
    }

// GRU recurrence, one WG per batch element. 512 threads; threads 2u and 2u+1
// co-own unit u: each holds HALF the k-range (64 f16-pairs) of all three gate
// columns (z: u, r: u+256, hh: u+512) => 192 U-VGPRs/thread, under the 256
// addressable-VGPR cap (the round-1 384-reg version spilled). Each thread
// reads only its half of h from LDS (256 B/step): 3x less LDS broadcast than
// the 768-thread kernel. Partner partial sums combine via __shfl_xor(.,1).
__global__ __launch_bounds__(512, 2) void gru_recur3(
    const half2v* __restrict__ Uh, const float* __restrict__ brec,
    const float* __restrict__ xp, float* __restrict__ seq_out,
    float* __restrict__ state_out, float* __restrict__ extra_out) {
    const int b = blockIdx.x, j = threadIdx.x;     // j in [0,512)
    const int u   = j >> 1;                        // unit index
    const int klo = j & 1;                         // 0: pairs 0..63, 1: 64..127

    __shared__ __align__(16) half2v h2s[2][NP];    // packed h (f16 pairs), dbuf

    // load this thread's half of the three U columns into VGPRs
    half2v u0[NH], u1[NH], u2[NH];
#pragma unroll
    for (int q = 0; q < NH; q++) {
        int row = klo * NH + q;
        u0[q] = Uh[row * N3 + u];
        u1[q] = Uh[row * N3 + u + UU];
        u2[q] = Uh[row * N3 + u + 2 * UU];
    }
    const float br0 = brec[u], br1 = brec[u + UU], br2 = brec[u + 2 * UU];

    if (j < NP) { half2v z0; z0.x = (_Float16)0.f; z0.y = (_Float16)0.f; h2s[0][j] = z0; }
    float hst = 0.f;                               // fp32 h state, in-register
    __syncthreads();

    const float* __restrict__ xpb = xp + (size_t)b * TT * N3;
    float xz = xpb[u], xr = xpb[u + UU], xh = xpb[u + 2 * UU];

    for (int t = 0; t < TT; t++) {
        // prefetch next step's x-projection
        const float* xn = xpb + (size_t)(t + 1 < TT ? t + 1 : t) * N3;
        float xzn = xn[u], xrn = xn[u + UU], xhn = xn[u + 2 * UU];

        // partial rec_g = sum_{k in my half} h[k] * U[k][col_g]
        float a0a = 0.f, a0b = 0.f, a1a = 0.f, a1b = 0.f, a2a = 0.f, a2b = 0.f;
        const float4* hb4 = (const float4*)h2s[t & 1] + (klo << 4);
#pragma unroll
        for (int p4 = 0; p4 < NH / 4; p4++) {
            float4 hv = hb4[p4];
            DOT4PAIRS(hv, 4 * p4);
        }
        // combine partner halves (adjacent lanes, same wave)
        float az = a0a + a0b; az += __shfl_xor(az, 1);
        float ar = a1a + a1b; ar += __shfl_xor(ar, 1);
        float ah = a2a + a2b; ah += __shfl_xor(ah, 1);

        // gates (computed redundantly on both partners; all thread-local)
        float z  = 1.f / (1.f + __expf(-(xz + az + br0)));
        float r  = 1.f / (1.f + __expf(-(xr + ar + br1)));
        float hh = xh + r * (ah + br2);
        hh = hh > 0.f ? hh : 0.f;
        float hn = z * hst + (1.f - z) * hh;
        hst = hn;

        // pack h into f16 pairs for next step's broadcast:
        // j=4p holds h[2p], j=4p+2 holds h[2p+1]
        float hq = __shfl_xor(hn, 2);
        if ((j & 3) == 0) {
            half2v pk; pk.x = (_Float16)hn; pk.y = (_Float16)hq;
            h2s[(t + 1) & 1][j >> 2] = pk;
        }
        if (seq_out && klo == 0)
            seq_out[(size_t)b * TT * UU + (size_t)t * UU + u] = hn;
        __syncthreads();                           // single barrier per step
        xz = xzn; xr = xrn; xh = xhn;
    }

    if (klo == 0) {
        state_out[b * UU + u] = hst;
        if (extra_out) extra_out[b * UU + u] = hst;
    }
}

extern "C" void kernel_launch(void* const* d_in, const int* in_sizes, int n_in,
                              void* d_out, int out_size, void* d_ws, size_t ws_size,
                              hipStream_t stream) {
    const float* x  = (const float*)d_in[0];
    const float* W1 = (const float*)d_in[1];
    const float* U1 = (const float*)d_in[2];
    const float* b1 = (const float*)d_in[3];
    const float* W2 = (const float*)d_in[4];
    const float* U2 = (const float*)d_in[5];
    const float* b2 = (const float*)d_in[6];
    float* out = (float*)d_out;

    half2v* U1h; hipGetSymbolAddress((void**)&U1h, HIP_SYMBOL(g_U1h));
    half2v* U2h; hipGetSymbolAddress((void**)&U2h, HIP_SYMBOL(g_U2h));
    float*  seq1; hipGetSymbolAddress((void**)&seq1, HIP_SYMBOL(g_seq1));
    float*  xp;   hipGetSymbolAddress((void**)&xp,   HIP_SYMBOL(g_xp));

    prep_uh<<<NP * N3 / 256, 256, 0, stream>>>(U1, U1h);
    prep_uh<<<NP * N3 / 256, 256, 0, stream>>>(U2, U2h);

    // layer 1
    gemm_k15<<<dim3(BB * TT / 8, 3), 256, 0, stream>>>(x, W1, b1, xp);
    gru_recur3<<<BB, 512, 0, stream>>>(U1h, b1 + N3, xp, seq1, out + BB * UU, nullptr);

    // layer 2
    gemm_xp<<<dim3(BB * TT / 64, N3 / 64), 256, 0, stream>>>(seq1, W2, b2, xp);
    gru_recur3<<<BB, 512, 0, stream>>>(U2h, b2 + N3, xp, nullptr, out + 2 * BB * UU, out);
}